// Round 4
// baseline (308.407 us; speedup 1.0000x reference)
//
#include <hip/hip_runtime.h>
#include <hip/hip_bf16.h>

#define VOCAB 100000
#define EMB   300
#define BATCH 2048
#define SEQ   256
#define NBLK  1024            // 4 blocks/CU on 256 CUs; <=128 VGPR -> co-resident
#define IPB   (BATCH / NBLK)  // 2 items per block

typedef float f4 __attribute__((ext_vector_type(4)));

// Single fused kernel:
//   Phase 1: p[v] = dot(W_emb[v,:], fc_w)  (streams 120 MB, 16 lanes/row,
//            4 rows/wave/iter; VOCAB % 4 == 0 so no bounds check needed)
//   Barrier: device-wide software barrier (all 1024 blocks co-resident)
//   Phase 2: out[b] = sigmoid(sum(p[tok])/len + bias) for this block's 2 items
// Tokens/lengths are preloaded into registers before phase 1 so their HBM
// latency hides under the streaming loop's first vmcnt drain.
__global__ void __launch_bounds__(256, 4) fused_kernel(
    const int* __restrict__ tokens, const int* __restrict__ lengths,
    const float* __restrict__ W, const float* __restrict__ fcw,
    const float* __restrict__ fcb, float* __restrict__ out,
    float* __restrict__ p, unsigned int* __restrict__ ctr) {
  const int tid  = threadIdx.x;
  const int lane = tid & 63;
  const int g    = lane >> 4;        // row within quad
  const int i    = lane & 15;        // lane within 16-lane group
  const int wave = ((blockIdx.x << 8) + tid) >> 6;
  const int nwaves = (NBLK << 8) >> 6;   // 4096 waves

  // ---- Preload phase-2 operands (overlap with phase-1 stream) ----
  const int b0 = blockIdx.x * IPB;
  int tok0 = tokens[(size_t)b0 * SEQ + tid];
  int tok1 = tokens[(size_t)(b0 + 1) * SEQ + tid];
  const int len0 = lengths[b0];
  const int len1 = lengths[b0 + 1];
  const float bias = fcb[0];
  asm volatile("" : "+v"(tok0), "+v"(tok1));  // pin loads before the loop

  const f4* fcw4 = (const f4*)fcw;
  const f4 zero = {0.f, 0.f, 0.f, 0.f};
  f4 w0 = fcw4[i];
  f4 w1 = fcw4[i + 16];
  f4 w2 = fcw4[i + 32];
  f4 w3 = fcw4[i + 48];
  f4 w4 = (i < 11) ? fcw4[i + 64] : zero;

  // ---- Phase 1: stream W_emb, write p ----
  for (int v0 = wave * 4; v0 < VOCAB; v0 += nwaves * 4) {
    const int v = v0 + g;
    const f4* r = (const f4*)(W + (size_t)v * EMB);
    f4 a0 = __builtin_nontemporal_load(&r[i]);
    f4 a1 = __builtin_nontemporal_load(&r[i + 16]);
    f4 a2 = __builtin_nontemporal_load(&r[i + 32]);
    f4 a3 = __builtin_nontemporal_load(&r[i + 48]);
    f4 a4 = (i < 11) ? __builtin_nontemporal_load(&r[i + 64]) : zero;
    f4 s = a0 * w0 + a1 * w1 + a2 * w2 + a3 * w3 + a4 * w4;
    float acc = s.x + s.y + s.z + s.w;
    acc += __shfl_xor(acc, 8, 16);
    acc += __shfl_xor(acc, 4, 16);
    acc += __shfl_xor(acc, 2, 16);
    acc += __shfl_xor(acc, 1, 16);
    if (i == 0) p[v] = acc;
  }

  // ---- Device-wide software barrier ----
  __threadfence();            // release: flush this thread's p stores to L3
  __syncthreads();
  if (tid == 0) {
    atomicAdd(ctr, 1u);       // device-scope by default
    while (__hip_atomic_load(ctr, __ATOMIC_RELAXED, __HIP_MEMORY_SCOPE_AGENT)
           < (unsigned)NBLK) {
      __builtin_amdgcn_s_sleep(2);
    }
  }
  __syncthreads();
  __threadfence();            // acquire: invalidate stale lines before p reads

  // ---- Phase 2: gather + reduce + sigmoid ----
  float x0 = (tid < len0) ? p[tok0] : 0.f;
  float x1 = (tid < len1) ? p[tok1] : 0.f;
  #pragma unroll
  for (int off = 32; off > 0; off >>= 1) {
    x0 += __shfl_down(x0, off, 64);
    x1 += __shfl_down(x1, off, 64);
  }
  __shared__ float part[2][4];
  const int w = tid >> 6;
  if (lane == 0) { part[0][w] = x0; part[1][w] = x1; }
  __syncthreads();
  if (tid == 0) {
    const float s0 = part[0][0] + part[0][1] + part[0][2] + part[0][3];
    const float s1 = part[1][0] + part[1][1] + part[1][2] + part[1][3];
    const float z0 = s0 / (float)len0 + bias;
    const float z1 = s1 / (float)len1 + bias;
    out[b0]     = 1.f / (1.f + expf(-z0));
    out[b0 + 1] = 1.f / (1.f + expf(-z1));
  }
}

extern "C" void kernel_launch(void* const* d_in, const int* in_sizes, int n_in,
                              void* d_out, int out_size, void* d_ws, size_t ws_size,
                              hipStream_t stream) {
  const int*   tokens  = (const int*)d_in[0];    // [B, L]
  const int*   lengths = (const int*)d_in[1];    // [B]
  const float* W_emb   = (const float*)d_in[2];  // [VOCAB, EMB]
  const float* fc_w    = (const float*)d_in[3];  // [1, EMB]
  const float* fc_b    = (const float*)d_in[4];  // [1]
  float* out = (float*)d_out;                    // [B, 1]

  float* p = (float*)d_ws;                                   // 400 KB table
  unsigned int* ctr = (unsigned int*)((char*)d_ws + 400000); // 128B-aligned

  // Barrier counter must be 0 at kernel start, every call (d_ws is poisoned
  // once and never re-poisoned). 4-byte memset is graph-capturable.
  hipMemsetAsync(ctr, 0, sizeof(unsigned int), stream);

  fused_kernel<<<NBLK, 256, 0, stream>>>(
      tokens, lengths, W_emb, fc_w, fc_b, out, p, ctr);
}

// Round 5
// 27.791 us; speedup vs baseline: 11.0975x; 11.0975x over previous
//
#include <hip/hip_runtime.h>
#include <hip/hip_bf16.h>

#define VOCAB 100000
#define EMB 300
#define BATCH 2048
#define SEQ 256

typedef float f4 __attribute__((ext_vector_type(4)));

// Kernel 1: p[v] = dot(W_emb[v, :], fc_w[:])  for v in [0, VOCAB)
// 16 lanes per row, 4 rows per wave per iteration. Row = 75 float4
// (16B-aligned, 300 % 4 == 0). Lane i of group g reads float4 idx
// {i, i+16, i+32, i+48} (+ i+64 if i<11) of row v0+g. One 4-step
// __shfl_xor width-16 reduce sums all four rows simultaneously.
// NOTE: plain (cache-allocating) loads on purpose — W_emb (120 MB) fits in
// the 256 MB Infinity Cache and stays resident across graph replays.
__global__ void __launch_bounds__(256) vocab_dot_kernel(
    const float* __restrict__ W, const float* __restrict__ fcw,
    float* __restrict__ p, int nrows) {
  const int lane = threadIdx.x & 63;
  const int g    = lane >> 4;        // group 0..3 (row within quad)
  const int i    = lane & 15;        // lane within group
  const int wave = (blockIdx.x * blockDim.x + threadIdx.x) >> 6;
  const int nwaves = (gridDim.x * blockDim.x) >> 6;

  const f4* fcw4 = (const f4*)fcw;
  const f4 zero = {0.f, 0.f, 0.f, 0.f};
  f4 w0 = fcw4[i];
  f4 w1 = fcw4[i + 16];
  f4 w2 = fcw4[i + 32];
  f4 w3 = fcw4[i + 48];
  f4 w4 = (i < 11) ? fcw4[i + 64] : zero;

  for (int v0 = wave * 4; v0 < nrows; v0 += nwaves * 4) {
    const int v = v0 + g;
    float acc = 0.f;
    if (v < nrows) {
      const f4* r = (const f4*)(W + (size_t)v * EMB);
      f4 a0 = r[i];
      f4 a1 = r[i + 16];
      f4 a2 = r[i + 32];
      f4 a3 = r[i + 48];
      f4 a4 = (i < 11) ? r[i + 64] : zero;
      f4 s = a0 * w0 + a1 * w1 + a2 * w2 + a3 * w3 + a4 * w4;
      acc = s.x + s.y + s.z + s.w;
    }
    // Segmented reduce: sums within each 16-lane group (all 4 rows at once).
    acc += __shfl_xor(acc, 8, 16);
    acc += __shfl_xor(acc, 4, 16);
    acc += __shfl_xor(acc, 2, 16);
    acc += __shfl_xor(acc, 1, 16);
    if (i == 0 && v < nrows) p[v] = acc;
  }
}

// Kernel 2: out[b] = sigmoid( (sum_{l<len} p[tok[b,l]]) / len + fc_b )
// One block (256 threads) per item; thread t handles position t (L == 256).
__global__ void __launch_bounds__(256) pool_sigmoid_kernel(
    const int* __restrict__ tokens, const int* __restrict__ lengths,
    const float* __restrict__ p, const float* __restrict__ fcb,
    float* __restrict__ out, int L) {
  __shared__ float part[4];
  const int b = blockIdx.x;
  const int t = threadIdx.x;
  const int len = lengths[b];

  float acc = 0.f;
  if (t < len) acc = p[tokens[(size_t)b * L + t]];

  #pragma unroll
  for (int off = 32; off > 0; off >>= 1)
    acc += __shfl_down(acc, off, 64);

  const int lane = t & 63, w = t >> 6;
  if (lane == 0) part[w] = acc;
  __syncthreads();
  if (t == 0) {
    float s = part[0] + part[1] + part[2] + part[3];
    float z = s / (float)len + fcb[0];
    out[b] = 1.0f / (1.0f + expf(-z));
  }
}

extern "C" void kernel_launch(void* const* d_in, const int* in_sizes, int n_in,
                              void* d_out, int out_size, void* d_ws, size_t ws_size,
                              hipStream_t stream) {
  const int*   tokens  = (const int*)d_in[0];    // [B, L]
  const int*   lengths = (const int*)d_in[1];    // [B]
  const float* W_emb   = (const float*)d_in[2];  // [VOCAB, EMB]
  const float* fc_w    = (const float*)d_in[3];  // [1, EMB]
  const float* fc_b    = (const float*)d_in[4];  // [1]
  float* out = (float*)d_out;                    // [B, 1]
  float* p   = (float*)d_ws;                     // VOCAB floats (400 KB)

  // Kernel 1: 2048 blocks x 256 threads = 8192 waves, 4 rows/wave/iter.
  vocab_dot_kernel<<<2048, 256, 0, stream>>>(W_emb, fc_w, p, VOCAB);

  // Kernel 2: one block per item.
  pool_sigmoid_kernel<<<BATCH, 256, 0, stream>>>(
      tokens, lengths, p, fc_b, out, SEQ);
}

// Round 6
// 26.676 us; speedup vs baseline: 11.5611x; 1.0418x over previous
//
#include <hip/hip_runtime.h>
#include <hip/hip_bf16.h>

#define VOCAB 100000
#define EMB 300
#define BATCH 2048
#define SEQ 256
#define NBLK1 3125   // 12500 waves x 8 rows/wave = exactly 100000 rows

typedef float f4 __attribute__((ext_vector_type(4)));
typedef int   i4 __attribute__((ext_vector_type(4)));

// Kernel 1: p[v] = dot(W_emb[v, :], fc_w[:])  for v in [0, VOCAB)
// 16 lanes per row, 4 rows per wave per iteration, exactly 2 iterations per
// wave (12500 waves x 8 rows = 100000 = VOCAB, no tail, no bounds checks).
// All 10 row-loads are issued before any FMA -> 10 outstanding f4 loads/lane.
// Row = 75 float4 (16B-aligned, 300 % 4 == 0): lane i of group g reads f4
// idx {i, i+16, i+32, i+48} (+ i+64 if i<11). Segmented 4-step __shfl_xor
// width-16 reduce sums all 4 rows of a quad simultaneously.
__global__ void __launch_bounds__(256) vocab_dot_kernel(
    const float* __restrict__ W, const float* __restrict__ fcw,
    float* __restrict__ p) {
  const int lane = threadIdx.x & 63;
  const int g    = lane >> 4;        // row within quad
  const int i    = lane & 15;        // lane within 16-lane group
  const int wave = (blockIdx.x * 256 + threadIdx.x) >> 6;  // 0..12499

  const f4* fcw4 = (const f4*)fcw;
  const f4 zero = {0.f, 0.f, 0.f, 0.f};
  f4 w0 = fcw4[i];
  f4 w1 = fcw4[i + 16];
  f4 w2 = fcw4[i + 32];
  f4 w3 = fcw4[i + 48];
  f4 w4 = (i < 11) ? fcw4[i + 64] : zero;

  const int v0 = wave * 8 + g;       // rows [8w .. 8w+7], this lane-group's 2
  const int v1 = v0 + 4;
  const f4* r0 = (const f4*)(W + (size_t)v0 * EMB);
  const f4* r1 = (const f4*)(W + (size_t)v1 * EMB);

  // Issue all loads up front.
  f4 a0 = __builtin_nontemporal_load(&r0[i]);
  f4 a1 = __builtin_nontemporal_load(&r0[i + 16]);
  f4 a2 = __builtin_nontemporal_load(&r0[i + 32]);
  f4 a3 = __builtin_nontemporal_load(&r0[i + 48]);
  f4 a4 = (i < 11) ? __builtin_nontemporal_load(&r0[i + 64]) : zero;
  f4 b0 = __builtin_nontemporal_load(&r1[i]);
  f4 b1 = __builtin_nontemporal_load(&r1[i + 16]);
  f4 b2 = __builtin_nontemporal_load(&r1[i + 32]);
  f4 b3 = __builtin_nontemporal_load(&r1[i + 48]);
  f4 b4 = (i < 11) ? __builtin_nontemporal_load(&r1[i + 64]) : zero;

  f4 s0 = a0 * w0 + a1 * w1 + a2 * w2 + a3 * w3 + a4 * w4;
  f4 s1 = b0 * w0 + b1 * w1 + b2 * w2 + b3 * w3 + b4 * w4;
  float acc0 = s0.x + s0.y + s0.z + s0.w;
  float acc1 = s1.x + s1.y + s1.z + s1.w;

  acc0 += __shfl_xor(acc0, 8, 16);
  acc1 += __shfl_xor(acc1, 8, 16);
  acc0 += __shfl_xor(acc0, 4, 16);
  acc1 += __shfl_xor(acc1, 4, 16);
  acc0 += __shfl_xor(acc0, 2, 16);
  acc1 += __shfl_xor(acc1, 2, 16);
  acc0 += __shfl_xor(acc0, 1, 16);
  acc1 += __shfl_xor(acc1, 1, 16);
  if (i == 0) {
    p[v0] = acc0;
    p[v1] = acc1;
  }
}

// Kernel 2: out[b] = sigmoid( (sum_{l<len} p[tok[b,l]]) / len + fc_b )
// One wave per item, 4 items per block. Lane reads int4 = 4 tokens (one
// coalesced 16B load covers the whole row of 256 tokens per wave), then 4
// independent gathers from the 400 KB p table (L2/L3-resident).
__global__ void __launch_bounds__(256) pool_sigmoid_kernel(
    const int* __restrict__ tokens, const int* __restrict__ lengths,
    const float* __restrict__ p, const float* __restrict__ fcb,
    float* __restrict__ out) {
  const int lane = threadIdx.x & 63;
  const int w    = threadIdx.x >> 6;
  const int b    = blockIdx.x * 4 + w;

  const int len = lengths[b];
  const i4 t = ((const i4*)(tokens + (size_t)b * SEQ))[lane];
  const int base = lane * 4;

  float acc = 0.f;
  if (base + 0 < len) acc += p[t[0]];
  if (base + 1 < len) acc += p[t[1]];
  if (base + 2 < len) acc += p[t[2]];
  if (base + 3 < len) acc += p[t[3]];

  #pragma unroll
  for (int off = 32; off > 0; off >>= 1)
    acc += __shfl_down(acc, off, 64);

  if (lane == 0) {
    const float z = acc / (float)len + fcb[0];
    out[b] = 1.0f / (1.0f + expf(-z));
  }
}

extern "C" void kernel_launch(void* const* d_in, const int* in_sizes, int n_in,
                              void* d_out, int out_size, void* d_ws, size_t ws_size,
                              hipStream_t stream) {
  const int*   tokens  = (const int*)d_in[0];    // [B, L]
  const int*   lengths = (const int*)d_in[1];    // [B]
  const float* W_emb   = (const float*)d_in[2];  // [VOCAB, EMB]
  const float* fc_w    = (const float*)d_in[3];  // [1, EMB]
  const float* fc_b    = (const float*)d_in[4];  // [1]
  float* out = (float*)d_out;                    // [B, 1]
  float* p   = (float*)d_ws;                     // VOCAB floats (400 KB)

  // Kernel 1: 3125 blocks x 256 threads = 12500 waves, 8 rows each, no tail.
  vocab_dot_kernel<<<NBLK1, 256, 0, stream>>>(W_emb, fc_w, p);

  // Kernel 2: one wave per item, 4 items per block.
  pool_sigmoid_kernel<<<BATCH / 4, 256, 0, stream>>>(
      tokens, lengths, p, fc_b, out);
}